// Round 13
// baseline (154.707 us; speedup 1.0000x reference)
//
#include <hip/hip_runtime.h>

// mRNN B=128, C=64, H=32, T=256 via MFMA 16x16x32 bf16, split-bf16 (hi+lo).
// R13 = R12 + ONE change: U-projection via MFMA (AU fragment) instead of
// per-lane FMAs + cross-q DS swizzles.
//   AU has U (hi/lo split) in A-row m=0 only (lanes n==0), zeros elsewhere;
//   D[0][n] = U . h[:,n] lands in reg0 of the q==0 lanes that store.
//   Removes 8 FMA/step + 32 shuffle ops + 2 DS latency windows per quad;
//   adds 3 off-critical-path MFMAs/step reading the existing B fragments.
//   U-proj error is per-output (does NOT feed the recurrence): ~1e2 at
//   output scale on top of absmax 4096, threshold 15155.
// NOTE: R6 bundled AU with the dir-template; R7 proved the template ALONE
// fails validation -> AU was never tested clean. This is that test.
//
// Hard constraints learned this session:
//  - DO NOT template/dual-inline on dir (R6/R7 fail; single body passes).
//  - DO NOT duplicate lanes for occupancy (R9).
//  - DO NOT split a chain across waves (R11).
//
// Layout-closed recurrence (R3/R5/R8/R12-verified): h kept as B-operand
// fragment; row perm rho(m)=8*(m>>2)+(m&3) (+4 tile1) makes lane (q,n)'s
// C/D output exactly its next-step B fragment; B k-slot (q,j) <-> physical
// row 8q+j (identity). No LDS anywhere.
//
// Precision (R5/R8/R12-verified): W=Whi+Wlo, h=hhi+hlo, hi=truncate (exact
// residual), lo=RNE; acc = relu( (Whi@hh) + (Wlo@hh + vinit + Whi@hl) ).
constexpr int Bn = 128, Cn = 64, Hn = 32, Tn = 256;

typedef __attribute__((ext_vector_type(8))) short short8;
typedef __attribute__((ext_vector_type(4))) float f32x4;
typedef __attribute__((ext_vector_type(4))) unsigned int u32x4;

// pack top16(y):top16(x) -> one u32 (low half = x's top16)
__device__ __forceinline__ unsigned pk_hi(unsigned y, unsigned x) {
  return __builtin_amdgcn_perm(y, x, 0x07060302u);
}

__device__ __forceinline__ void wsplit(float w, short& hi, short& lo) {
  unsigned u = __float_as_uint(w);
  float r = w - __uint_as_float(u & 0xffff0000u);   // exact residual
  unsigned ru = __float_as_uint(r) + 0x8000u;       // RNE-ish lo
  hi = (short)(u >> 16);
  lo = (short)(ru >> 16);
}

__global__ __launch_bounds__(64, 1)
void mrnn_scan(const float* __restrict__ x, const float* __restrict__ m,
               const float* __restrict__ d,
               const float* __restrict__ Wf, const float* __restrict__ Vf,
               const float* __restrict__ cf,
               const float* __restrict__ Wb, const float* __restrict__ Vb,
               const float* __restrict__ cb,
               const float* __restrict__ U,
               float* __restrict__ pf_out, float* __restrict__ pb_out) {
  const int bid = blockIdx.x;
  const int dir = bid >> 9;                 // 0 fwd, 1 bwd
  const int c   = (bid >> 3) & (Cn - 1);
  const int g   = bid & 7;                  // batch group of 16
  const int tid = threadIdx.x;              // 0..63, one wave
  const int q = tid >> 4;
  const int n = tid & 15;
  const int b = g * 16 + n;

  const float* W  = dir ? Wb : Wf;
  const float* V  = dir ? Vb : Vf;
  const float* cc = dir ? cb : cf;

  // ---- A fragments: A[m=lane&15][k=8q+j], row perm rho(m)=8*(m>>2)+(m&3)
  const int ra0 = 8 * (n >> 2) + (n & 3);
  const int ra1 = ra0 + 4;
  short8 A0h, A0l, A1h, A1l;
#pragma unroll
  for (int j = 0; j < 8; ++j) {
    short hi, lo;
    wsplit(W[(c * Hn + ra0) * Hn + 8 * q + j], hi, lo); A0h[j] = hi; A0l[j] = lo;
    wsplit(W[(c * Hn + ra1) * Hn + 8 * q + j], hi, lo); A1h[j] = hi; A1l[j] = lo;
  }

  // ---- U as an A fragment: row m=0 (lanes n==0) holds U[8q+j], rest zero.
  // k-slot (q,j) <-> physical h row 8q+j (identity), matching the B layout.
  short8 AUh = {0, 0, 0, 0, 0, 0, 0, 0};
  short8 AUl = {0, 0, 0, 0, 0, 0, 0, 0};
  if (n == 0) {
#pragma unroll
    for (int j = 0; j < 8; ++j) {
      short hi, lo;
      wsplit(U[c * 2 * Hn + dir * Hn + 8 * q + j], hi, lo);
      AUh[j] = hi; AUl[j] = lo;
    }
  }

  // ---- per-lane D rows: tile0 -> 8q+r, tile1 -> 8q+4+r
  float v0x[4], v0y[4], v0z[4], bs0[4];
  float v1x[4], v1y[4], v1z[4], bs1[4];
#pragma unroll
  for (int r = 0; r < 4; ++r) {
    const int row0 = 8 * q + r, row1 = row0 + 4;
    const float* vp0 = V + (c * Hn + row0) * 3;
    v0x[r] = vp0[0]; v0y[r] = vp0[1]; v0z[r] = vp0[2];
    bs0[r] = cc[c * Hn + row0];
    const float* vp1 = V + (c * Hn + row1) * 3;
    v1x[r] = vp1[0]; v1y[r] = vp1[1]; v1z[r] = vp1[2];
    bs1[r] = cc[c * Hn + row1];
  }

  // ---- state (B fragments)
  u32x4 Bh = {0u, 0u, 0u, 0u};
  u32x4 Bl = {0u, 0u, 0u, 0u};
  const f32x4 z4 = {0.f, 0.f, 0.f, 0.f};

  const long base = ((long)b * Cn + c) * Tn;
  const float* px = x + base;
  const float* pm = m + base;
  const float* pd = d + base;
  float* pout = (dir ? pb_out : pf_out) + base;

  // input schedule (verified): fwd step t reads idx max(t-1,0);
  // bwd step s reads idx min(T-s, T-1). Carry + aligned 8-wide prefetch.
  float cx, cm2, cd2;
  f32x4 qx0, qx1, qm0, qm1, qd0, qd1;
  if (!dir) {
    cx = px[0]; cm2 = pm[0]; cd2 = pd[0];
    qx0 = *(const f32x4*)px;        qx1 = *(const f32x4*)(px + 4);
    qm0 = *(const f32x4*)pm;        qm1 = *(const f32x4*)(pm + 4);
    qd0 = *(const f32x4*)pd;        qd1 = *(const f32x4*)(pd + 4);
  } else {
    cx = px[Tn - 1]; cm2 = pm[Tn - 1]; cd2 = pd[Tn - 1];
    qx0 = *(const f32x4*)(px + Tn - 8); qx1 = *(const f32x4*)(px + Tn - 4);
    qm0 = *(const f32x4*)(pm + Tn - 8); qm1 = *(const f32x4*)(pm + Tn - 4);
    qd0 = *(const f32x4*)(pd + Tn - 8); qd1 = *(const f32x4*)(pd + Tn - 4);
  }

  for (int t0 = 0; t0 < Tn; t0 += 8) {
    int qn_ = dir ? (Tn - 16 - t0) : (t0 + 8);
    if (qn_ < 0) qn_ = 0;
    if (qn_ > Tn - 8) qn_ = Tn - 8;
    const f32x4 nx0 = *(const f32x4*)(px + qn_), nx1 = *(const f32x4*)(px + qn_ + 4);
    const f32x4 nm0 = *(const f32x4*)(pm + qn_), nm1 = *(const f32x4*)(pm + qn_ + 4);
    const f32x4 nd0 = *(const f32x4*)(pd + qn_), nd1 = *(const f32x4*)(pd + qn_ + 4);

    // v[0..7] = the 8 loaded values per stream
    float vxa[8] = {qx0.x, qx0.y, qx0.z, qx0.w, qx1.x, qx1.y, qx1.z, qx1.w};
    float vma[8] = {qm0.x, qm0.y, qm0.z, qm0.w, qm1.x, qm1.y, qm1.z, qm1.w};
    float vda[8] = {qd0.x, qd0.y, qd0.z, qd0.w, qd1.x, qd1.y, qd1.z, qd1.w};
    float inx[8], inm[8], ind[8];
    inx[0] = cx; inm[0] = cm2; ind[0] = cd2;
    if (!dir) {
#pragma unroll
      for (int k = 1; k < 8; ++k) {
        inx[k] = vxa[k - 1]; inm[k] = vma[k - 1]; ind[k] = vda[k - 1];
      }
      cx = vxa[7]; cm2 = vma[7]; cd2 = vda[7];
    } else {
#pragma unroll
      for (int k = 1; k < 8; ++k) {
        inx[k] = vxa[8 - k]; inm[k] = vma[8 - k]; ind[k] = vda[8 - k];
      }
      cx = vxa[0]; cm2 = vma[0]; cd2 = vda[0];
    }

    float pacc[8];
#pragma unroll
    for (int u = 0; u < 8; ++u) {
      const float ix = inx[u], im = inm[u], idv = ind[u];
      f32x4 vi0, vi1;
#pragma unroll
      for (int r = 0; r < 4; ++r) {
        vi0[r] = fmaf(v0x[r], ix, fmaf(v0y[r], im, fmaf(v0z[r], idv, bs0[r])));
        vi1[r] = fmaf(v1x[r], ix, fmaf(v1y[r], im, fmaf(v1z[r], idv, bs1[r])));
      }
      const short8 bh = __builtin_bit_cast(short8, Bh);
      const short8 bl = __builtin_bit_cast(short8, Bl);
      // two depth-2 chains per tile (R12-verified):
      //   side = Wlo@hh + vinit -> + Whi@hl ; main = Whi@hh + 0
      f32x4 s0 = __builtin_amdgcn_mfma_f32_16x16x32_bf16(A0l, bh, vi0, 0, 0, 0);
      f32x4 s1 = __builtin_amdgcn_mfma_f32_16x16x32_bf16(A1l, bh, vi1, 0, 0, 0);
      f32x4 a0 = __builtin_amdgcn_mfma_f32_16x16x32_bf16(A0h, bh, z4, 0, 0, 0);
      f32x4 a1 = __builtin_amdgcn_mfma_f32_16x16x32_bf16(A1h, bh, z4, 0, 0, 0);
      s0 = __builtin_amdgcn_mfma_f32_16x16x32_bf16(A0h, bl, s0, 0, 0, 0);
      s1 = __builtin_amdgcn_mfma_f32_16x16x32_bf16(A1h, bl, s1, 0, 0, 0);
      f32x4 acc0, acc1;
#pragma unroll
      for (int r = 0; r < 4; ++r) {
        acc0[r] = fmaxf(a0[r] + s0[r], 0.f);
        acc1[r] = fmaxf(a1[r] + s1[r], 0.f);
      }
      // repack state: hi = truncate via v_perm; lo = exact residual + RNE
      const unsigned h00 = __float_as_uint(acc0[0]), h01 = __float_as_uint(acc0[1]);
      const unsigned h02 = __float_as_uint(acc0[2]), h03 = __float_as_uint(acc0[3]);
      const unsigned h10 = __float_as_uint(acc1[0]), h11 = __float_as_uint(acc1[1]);
      const unsigned h12 = __float_as_uint(acc1[2]), h13 = __float_as_uint(acc1[3]);
      Bh[0] = pk_hi(h01, h00); Bh[1] = pk_hi(h03, h02);
      Bh[2] = pk_hi(h11, h10); Bh[3] = pk_hi(h13, h12);
      unsigned ru[8];
#pragma unroll
      for (int r = 0; r < 4; ++r) {
        ru[r]     = __float_as_uint(acc0[r] - __uint_as_float(__float_as_uint(acc0[r]) & 0xffff0000u)) + 0x8000u;
        ru[4 + r] = __float_as_uint(acc1[r] - __uint_as_float(__float_as_uint(acc1[r]) & 0xffff0000u)) + 0x8000u;
      }
      Bl[0] = pk_hi(ru[1], ru[0]); Bl[1] = pk_hi(ru[3], ru[2]);
      Bl[2] = pk_hi(ru[5], ru[4]); Bl[3] = pk_hi(ru[7], ru[6]);

      // U-projection via MFMA on the fresh B fragments: D[0][n] = U . h[:,n]
      // lands in reg0 of the q==0 lanes. Off the recurrence critical path.
      const short8 bh2 = __builtin_bit_cast(short8, Bh);
      const short8 bl2 = __builtin_bit_cast(short8, Bl);
      f32x4 up = __builtin_amdgcn_mfma_f32_16x16x32_bf16(AUh, bh2, z4, 0, 0, 0);
      up = __builtin_amdgcn_mfma_f32_16x16x32_bf16(AUl, bh2, up, 0, 0, 0);
      up = __builtin_amdgcn_mfma_f32_16x16x32_bf16(AUh, bl2, up, 0, 0, 0);
      pacc[u] = up[0];
    }

    if (q == 0) {
      if (!dir) {
        f32x4 o0 = {pacc[0], pacc[1], pacc[2], pacc[3]};
        f32x4 o1 = {pacc[4], pacc[5], pacc[6], pacc[7]};
        *(f32x4*)(pout + t0) = o0;
        *(f32x4*)(pout + t0 + 4) = o1;
      } else {
        // positions Tn-8-t0+j hold step t0+(7-j)  (pre-reversed)
        f32x4 o0 = {pacc[7], pacc[6], pacc[5], pacc[4]};
        f32x4 o1 = {pacc[3], pacc[2], pacc[1], pacc[0]};
        *(f32x4*)(pout + (Tn - 8 - t0)) = o0;
        *(f32x4*)(pout + (Tn - 4 - t0)) = o1;
      }
    }
    qx0 = nx0; qx1 = nx1; qm0 = nm0; qm1 = nm1; qd0 = nd0; qd1 = nd1;
  }
}

// out[i] = relu(pf[i] + pb[i] + c0[c]); pf staged in d_out, pb pre-reversed.
__global__ __launch_bounds__(256)
void mrnn_combine(const float* __restrict__ pb, const float* __restrict__ c0,
                  float* __restrict__ out) {
  const int i4 = blockIdx.x * 256 + threadIdx.x;
  const int c = (i4 >> 6) & (Cn - 1);
  const float c0v = c0[c];
  float4 a = ((const float4*)out)[i4];
  const float4 bb = ((const float4*)pb)[i4];
  a.x = fmaxf(a.x + bb.x + c0v, 0.f);
  a.y = fmaxf(a.y + bb.y + c0v, 0.f);
  a.z = fmaxf(a.z + bb.z + c0v, 0.f);
  a.w = fmaxf(a.w + bb.w + c0v, 0.f);
  ((float4*)out)[i4] = a;
}

extern "C" void kernel_launch(void* const* d_in, const int* in_sizes, int n_in,
                              void* d_out, int out_size, void* d_ws, size_t ws_size,
                              hipStream_t stream) {
  const float* x  = (const float*)d_in[0];
  const float* m  = (const float*)d_in[1];
  const float* dd = (const float*)d_in[2];
  const float* Wf = (const float*)d_in[3];
  const float* Vf = (const float*)d_in[4];
  const float* cf = (const float*)d_in[5];
  const float* Wb = (const float*)d_in[6];
  const float* Vb = (const float*)d_in[7];
  const float* cb = (const float*)d_in[8];
  const float* U  = (const float*)d_in[9];
  const float* c0 = (const float*)d_in[10];
  float* out = (float*)d_out;
  float* pb  = (float*)d_ws;   // B*C*T floats = 8 MB scratch

  mrnn_scan<<<1024, 64, 0, stream>>>(x, m, dd, Wf, Vf, cf, Wb, Vb, cb, U, out, pb);
  mrnn_combine<<<(Bn * Cn * Tn) / (256 * 4), 256, 0, stream>>>(pb, c0, out);
}